// Round 17
// baseline (160.348 us; speedup 1.0000x reference)
//
#include <hip/hip_runtime.h>
#include <hip/hip_fp16.h>

// Problem constants (B,C,H,W = 2,3,96,96; D=32)
#define BB 2
#define CC 3
#define NN 9216   // 96*96
#define DD 32
#define NSPLIT 4                      // waves per block (key-quarters)
#define KSPLIT 2                      // blocks per 32-query group
#define KEYS_PER_WAVE (NN / (KSPLIT * NSPLIT))  // 1152
#define CHUNKS (KEYS_PER_WAVE / 64)   // 18
#define NGROUP (BB * NN / 32)         // 576 query groups
#define L2E 1.44269504f
#define SZH ((size_t)BB * NN * DD)    // halves per prep buffer (589,824)

typedef _Float16 half8 __attribute__((ext_vector_type(8)));
typedef _Float16 half4v __attribute__((ext_vector_type(4)));
typedef __fp16 fp16x2 __attribute__((ext_vector_type(2)));
typedef float float4v __attribute__((ext_vector_type(4)));

#define MFMA_K32(a, b, c) __builtin_amdgcn_mfma_f32_16x16x32_f16((a), (b), (c), 0, 0, 0)

// ---------------------------------------------------------------------------
// Fused prep. Blocks [0,288): K single-fp16 (fH) + Q hi/lo split (gH,gL),
// Q pre-scaled by log2(e). R17: K is stored KEY-PERMUTED within each 32-key
// group — mem position b*16+q*4+j holds actual key q*8+b*4+j — so that QK's
// C-layout (lane=query, regs = keys quad*4+j per 16-key blk) lands P directly
// in PV's B-fragment layout (lane=query, k-slots quad*8+e). V (hP) stays
// LINEAR, defining the k-slot <-> actual-key identity for the A-operand.
// Softmax and PV are permutation-invariant, so results are bit-identical.
// Blocks [288,324): PROJECTED V — hP[c][n] plus a ONES row 3 (PV MFMA's
// row-3 accumulator computes the softmax denominator L for free).
// ---------------------------------------------------------------------------
__global__ __launch_bounds__(256) void prep_kernel(
    const float* __restrict__ img,
    const float* __restrict__ kw, const float* __restrict__ kb,
    const float* __restrict__ qw, const float* __restrict__ qb,
    const float* __restrict__ vw, const float* __restrict__ vb,
    const float* __restrict__ ow,
    _Float16* __restrict__ fH,
    _Float16* __restrict__ gH, _Float16* __restrict__ gL,
    _Float16* __restrict__ hP)
{
    __shared__ float wsm[256];   // kw[96] | qw[96] | kb[32] | qb[32]
    __shared__ float cwb[12];
    int bid = blockIdx.x;
    int t = threadIdx.x;
    if (bid < 288) {
        float v;
        if (t < 96)       v = kw[t];
        else if (t < 192) v = qw[t - 96];
        else if (t < 224) v = kb[t - 192];
        else              v = qb[t - 224];
        wsm[t] = v;
        __syncthreads();

        int id = bid * 256 + t;                    // [0, BB*NN*4)
        int part = id & 3;
        int n = (id >> 2) % NN;
        int b = (id >> 2) / NN;
        const float* xb = img + (size_t)b * CC * NN + n;
        float x0 = xb[0], x1 = xb[NN], x2 = xb[2 * NN];
        half8 fh, gh, gl;
#pragma unroll
        for (int j = 0; j < 8; j++) {
            int d = part * 8 + j;
            float fv = wsm[d * 3 + 0] * x0 + wsm[d * 3 + 1] * x1 +
                       wsm[d * 3 + 2] * x2 + wsm[192 + d];
            float gv = (wsm[96 + d * 3 + 0] * x0 + wsm[96 + d * 3 + 1] * x1 +
                        wsm[96 + d * 3 + 2] * x2 + wsm[224 + d]) * L2E;
            _Float16 ghi = (_Float16)gv;
            fh[j] = (_Float16)fv;
            gh[j] = ghi; gl[j] = (_Float16)(gv - (float)ghi);
        }
        // K write: permuted position within the 32-key group (see header)
        int within = n & 31;
        int q  = within >> 3;      // 0..3
        int rm = within & 7;       // 0..7
        int bh = rm >> 2;          // 0..1
        int jj = rm & 3;           // 0..3
        int nperm = (n & ~31) | (bh << 4) | (q << 2) | jj;
        *(half8*)(fH + ((size_t)b * NN + nperm) * DD + part * 8) = fh;
        size_t off = ((size_t)b * NN + n) * DD + part * 8;
        *(half8*)(gH + off) = gh;
        *(half8*)(gL + off) = gl;
    } else {
        if (t < 9) {
            int c = t / 3, k = t % 3;
            float s = 0.f;
#pragma unroll
            for (int d = 0; d < DD; d++) s += ow[c * DD + d] * vw[d * 3 + k];
            cwb[t] = s;
        } else if (t < 12) {
            int c = t - 9;
            float s = 0.f;
#pragma unroll
            for (int d = 0; d < DD; d++) s += ow[c * DD + d] * vb[d];
            cwb[9 + c] = s;
        }
        __syncthreads();
        const int N8 = NN / 8;
        int id = (bid - 288) * 256 + t;            // [0, BB*4*N8) = 9216
        int n8 = id % N8;
        int row = (id / N8) & 3;
        int b = id / (N8 * 4);
        half8 hv = {1, 1, 1, 1, 1, 1, 1, 1};       // row 3: ONES (L computation)
        if (row < 3) {
            const float* xb = img + (size_t)b * CC * NN + n8 * 8;
            float w0 = cwb[row * 3 + 0], w1 = cwb[row * 3 + 1],
                  w2 = cwb[row * 3 + 2], bv = cwb[9 + row];
#pragma unroll
            for (int j = 0; j < 8; j++)
                hv[j] = (_Float16)(w0 * xb[j] + w1 * xb[NN + j] + w2 * xb[2 * NN + j] + bv);
        }
        *(half8*)(hP + ((size_t)(b * 4 + row)) * NN + n8 * 8) = hv;
    }
}

// ---------------------------------------------------------------------------
// Per-tile softmax + IN-REGISTER pack (R17: no LDS — P goes straight into
// PV's B-fragment registers; the key permutation in prep makes the layouts
// coincide). Scores arrive RELATIVE (QK C-init = -mrun, R16); common path is
// P = exp2(s) with no subtracts and a compare against THR=8. The trigger
// branch (rare) does the cross-lane max, rescales acc, subtracts delta, and
// bumps mrun. pa covers keys 0..31 (s[0],s[1]), pb keys 32..63 (s[2],s[3]):
// B-frag element e of quad q <-> actual key q*8+e, by construction.
// ---------------------------------------------------------------------------
__device__ __forceinline__ void softmax_pack(float4v (&s)[4], float& mrun,
                                             float4v& acc, half8& pa, half8& pb)
{
    float a0 = fmaxf(fmaxf(s[0][0], s[0][1]), s[0][2]);
    float a1 = fmaxf(fmaxf(s[0][3], s[1][0]), s[1][1]);
    float a2 = fmaxf(fmaxf(s[1][2], s[1][3]), s[2][0]);
    float a3 = fmaxf(fmaxf(s[2][1], s[2][2]), s[2][3]);
    float a4 = fmaxf(fmaxf(s[3][0], s[3][1]), s[3][2]);
    float lmax = fmaxf(fmaxf(fmaxf(a0, a1), fmaxf(a2, a3)), fmaxf(a4, s[3][3]));
    if (__any(lmax > 8.f)) {
        float mx = fmaxf(lmax, __shfl_xor(lmax, 16, 64));
        mx = fmaxf(mx, __shfl_xor(mx, 32, 64));     // per-column max (quads)
        float d = fmaxf(mx, 0.f);                   // monotone running max
        float alpha = __builtin_amdgcn_exp2f(-d);
#pragma unroll
        for (int r = 0; r < 4; r++) acc[r] *= alpha;   // incl. L row
        mrun += d;
#pragma unroll
        for (int blk = 0; blk < 4; blk++)
#pragma unroll
            for (int j = 0; j < 4; j++) s[blk][j] -= d;   // trigger-only subs
    }
    union { fp16x2 h2[4]; half8 h8; } ua, ub;
    ua.h2[0] = __builtin_amdgcn_cvt_pkrtz(__builtin_amdgcn_exp2f(s[0][0]),
                                          __builtin_amdgcn_exp2f(s[0][1]));
    ua.h2[1] = __builtin_amdgcn_cvt_pkrtz(__builtin_amdgcn_exp2f(s[0][2]),
                                          __builtin_amdgcn_exp2f(s[0][3]));
    ua.h2[2] = __builtin_amdgcn_cvt_pkrtz(__builtin_amdgcn_exp2f(s[1][0]),
                                          __builtin_amdgcn_exp2f(s[1][1]));
    ua.h2[3] = __builtin_amdgcn_cvt_pkrtz(__builtin_amdgcn_exp2f(s[1][2]),
                                          __builtin_amdgcn_exp2f(s[1][3]));
    ub.h2[0] = __builtin_amdgcn_cvt_pkrtz(__builtin_amdgcn_exp2f(s[2][0]),
                                          __builtin_amdgcn_exp2f(s[2][1]));
    ub.h2[1] = __builtin_amdgcn_cvt_pkrtz(__builtin_amdgcn_exp2f(s[2][2]),
                                          __builtin_amdgcn_exp2f(s[2][3]));
    ub.h2[2] = __builtin_amdgcn_cvt_pkrtz(__builtin_amdgcn_exp2f(s[3][0]),
                                          __builtin_amdgcn_exp2f(s[3][1]));
    ub.h2[3] = __builtin_amdgcn_cvt_pkrtz(__builtin_amdgcn_exp2f(s[3][2]),
                                          __builtin_amdgcn_exp2f(s[3][3]));
    pa = ua.h8; pb = ub.h8;
}

// ---------------------------------------------------------------------------
// Flash attention PARTIAL, cross-block split-K x2, 4 waves/block, 2 Q-tiles
// per wave. R17: P never touches LDS — QK's output is packed in-register
// into PV's B-fragments (key-permuted fH makes layouts coincide). This
// deletes 8 ds_writes + 4 ds_reads + lgkmcnt waits per chunk AND the
// 3.98M/dispatch LDS bank conflicts (P's 144B row stride) present since R0.
// LDS shrinks 18.4KB -> 9KB (merge buffers only). K single-fp16 (R15),
// C-init = -mrun fold (R16), single-K-buffer refill pipeline (R9),
// waves_per_eu(6,6) (proven no-spill at VGPR 40; ~+16 regs here).
// L is produced by the PV MFMA's ones-row (acc reg 3).
// ---------------------------------------------------------------------------
__global__ __launch_bounds__(256)
__attribute__((amdgpu_waves_per_eu(6, 6)))
void attn_partial_kernel(
    const _Float16* __restrict__ ws,
    float* __restrict__ pnum, float* __restrict__ pM)
{
    const _Float16* fH = ws;                 // K hi (key-permuted)
    const _Float16* gH = ws + SZH;           // Q hi (gL = +SZH)
    const _Float16* hP = ws + 3 * SZH;       // projected V (linear)

    const int gb = blockIdx.x;             // 0 .. NGROUP*KSPLIT-1
    const int g  = gb / KSPLIT;            // query group
    const int ks = gb % KSPLIT;            // key-split id
    const int b = g / (NN / 32);
    const int m0 = (g % (NN / 32)) * 32;
    const int tid = threadIdx.x;
    const int w = tid >> 6;                // wave id 0..3 (key-quarter)
    const int lane = tid & 63;
    const int l16 = lane & 15;
    const int quad = lane >> 4;

    // Merge buffers only (9 KB — P staging is gone)
    __shared__ __align__(16) struct {
        float acc[NSPLIT][4][33];
        float mbuf[NSPLIT][32];
    } sm;

    // Q B-fragments for both tiles (hi + lo, log2e-scaled); gL = gH + SZH
    const _Float16* gHb = gH + ((size_t)b * NN + m0 + l16) * DD + quad * 8;
    half8 qh0 = *(const half8*)(gHb);
    half8 ql0 = *(const half8*)(gHb + SZH);
    half8 qh1 = *(const half8*)(gHb + (size_t)16 * DD);
    half8 ql1 = *(const half8*)(gHb + SZH + (size_t)16 * DD);

    float4v acc0 = {0,0,0,0};              // tile0: C[row][m=l16]; row3 = L
    float4v acc1 = {0,0,0,0};              // tile1
    float mrun0 = 0.f;                     // per-COLUMN running max, rel. 0
    float mrun1 = 0.f;

    const int nbase = ks * (NN / KSPLIT) + w * KEYS_PER_WAVE;
    // hP^T A-frag pointer: row = min(l16,3) (rows 3..15 read the ONES row)
    const int vrow = (l16 < 3) ? l16 : 3;
    const _Float16* vp = hP + ((size_t)(b * 4 + vrow)) * NN + nbase + quad * 8;
    const _Float16* kp = fH + ((size_t)b * NN + nbase + l16) * DD + quad * 8;

    // ---- prologue: chunk 0's K resident in the (single) K buffer
    half8 kC[4];
#pragma unroll
    for (int blk = 0; blk < 4; blk++)
        kC[blk] = *(const half8*)(kp + (size_t)(blk * 16) * DD);
    kp += (size_t)64 * DD;                 // -> chunk 1

    for (int c = 0; c < CHUNKS; ++c) {
        float4v s[4];
        half8 pa0, pb0, pa1, pb1;
        // ---- QK tile 0: C-init = -mrun0 folds the softmax shift for free
        {
            float4v zm0 = {-mrun0, -mrun0, -mrun0, -mrun0};
#pragma unroll
            for (int blk = 0; blk < 4; blk++) {
                float4v t0 = MFMA_K32(kC[blk], ql0, zm0);
                s[blk] = MFMA_K32(kC[blk], qh0, t0);
            }
        }
        // V frags for THIS chunk: issued here, used in PV (~300+ cyc cover)
        half8 vA0 = *(const half8*)(vp);
        half8 vA1 = *(const half8*)(vp + 32);

        softmax_pack(s, mrun0, acc0, pa0, pb0);   // s dies here

        // ---- QK tile 1 (C-init = -mrun1); refill kC[blk] right after its
        //      last read (WAR), covered by sm1+PV (~250 cyc). Final iteration
        //      over-reads <=1 KB into the adjacent buffer (unused).
        {
            float4v zm1 = {-mrun1, -mrun1, -mrun1, -mrun1};
#pragma unroll
            for (int blk = 0; blk < 4; blk++) {
                float4v t1 = MFMA_K32(kC[blk], ql1, zm1);
                s[blk] = MFMA_K32(kC[blk], qh1, t1);
                kC[blk] = *(const half8*)(kp + (size_t)(blk * 16) * DD);
            }
        }
        kp += (size_t)64 * DD;

        softmax_pack(s, mrun1, acc1, pa1, pb1);

        // ---- PV: A = hP^T (3 rows + ONES pad), B = P (REGISTERS)
        //      => C[row=c, col=m=l16], row 3 accumulates L
        acc0 = MFMA_K32(vA0, pa0, acc0);
        acc0 = MFMA_K32(vA1, pb0, acc0);
        acc1 = MFMA_K32(vA0, pa1, acc1);
        acc1 = MFMA_K32(vA1, pb1, acc1);
        vp += 64;
    }

    // ---- write per-wave partials (fp32) for the in-block merge
    if (quad == 0) {
#pragma unroll
        for (int r = 0; r < 4; r++) {      // rows c=0..2 and L (r=3)
            sm.acc[w][r][l16]      = acc0[r];
            sm.acc[w][r][l16 + 16] = acc1[r];
        }
        sm.mbuf[w][l16]      = mrun0;
        sm.mbuf[w][l16 + 16] = mrun1;
    }
    __syncthreads();

    // ---- merge NSPLIT waves -> un-normalized block partial -> global
    if (tid < 4 * 32) {
        int c = tid >> 5, m = tid & 31;    // c=3 row is L
        float M = sm.mbuf[0][m];
#pragma unroll
        for (int s2 = 1; s2 < NSPLIT; s2++) M = fmaxf(M, sm.mbuf[s2][m]);
        float v = 0.f;
#pragma unroll
        for (int s2 = 0; s2 < NSPLIT; s2++)
            v += sm.acc[s2][c][m] * __builtin_amdgcn_exp2f(sm.mbuf[s2][m] - M);
        pnum[(size_t)gb * 128 + tid] = v;
        if (c == 0) pM[gb * 32 + m] = M;
    }
}

// ---------------------------------------------------------------------------
// Final merge: KSPLIT-way log-sum-exp combine of the block partials, + ob,
// clamp. L lives in pnum row 3 (from the MFMA ones-row).
// ---------------------------------------------------------------------------
__global__ __launch_bounds__(128) void merge_kernel(
    const float* __restrict__ pnum, const float* __restrict__ pM,
    const float* __restrict__ ob, float* __restrict__ out)
{
    const int g = blockIdx.x;              // 0 .. NGROUP-1
    const int b = g / (NN / 32);
    const int m0 = (g % (NN / 32)) * 32;
    const int tid = threadIdx.x;

    if (tid < CC * 32) {
        int c = tid >> 5, m = tid & 31;
        int base = g * KSPLIT;
        float M = pM[base * 32 + m];
#pragma unroll
        for (int k = 1; k < KSPLIT; k++) M = fmaxf(M, pM[(base + k) * 32 + m]);
        float num = 0.f, L = 0.f;
#pragma unroll
        for (int k = 0; k < KSPLIT; k++) {
            float e = __builtin_amdgcn_exp2f(pM[(base + k) * 32 + m] - M);
            num += pnum[(size_t)(base + k) * 128 + c * 32 + m] * e;
            L   += pnum[(size_t)(base + k) * 128 + 96 + m] * e;
        }
        float o = num / L + ob[c];
        o = fminf(1.f, fmaxf(-1.f, o));
        out[((size_t)b * CC + c) * NN + m0 + m] = o;
    }
}

extern "C" void kernel_launch(void* const* d_in, const int* in_sizes, int n_in,
                              void* d_out, int out_size, void* d_ws, size_t ws_size,
                              hipStream_t stream) {
    const float* img = (const float*)d_in[0];
    const float* kw  = (const float*)d_in[1];
    const float* kb  = (const float*)d_in[2];
    const float* qw  = (const float*)d_in[3];
    const float* qb  = (const float*)d_in[4];
    const float* vw  = (const float*)d_in[5];
    const float* vb  = (const float*)d_in[6];
    const float* ow  = (const float*)d_in[7];
    const float* ob  = (const float*)d_in[8];
    float* out = (float*)d_out;

    // Workspace: fH,gH,gL fp16 (3.5 MB) + hP fp16 [B][4][N] (148 KB)
    // + pnum (590 KB) + pM (147 KB) ~= 4.4 MB
    _Float16* fH = (_Float16*)d_ws;
    _Float16* gH = fH + SZH;
    _Float16* gL = gH + SZH;
    _Float16* hP = gL + SZH;
    float* pnum = (float*)(hP + (size_t)BB * 4 * NN);
    float* pM   = pnum + (size_t)NGROUP * KSPLIT * 128;

    prep_kernel<<<324, 256, 0, stream>>>(img, kw, kb, qw, qb, vw, vb, ow,
                                         fH, gH, gL, hP);
    attn_partial_kernel<<<NGROUP * KSPLIT, 256, 0, stream>>>(
        (const _Float16*)d_ws, pnum, pM);
    merge_kernel<<<NGROUP, 128, 0, stream>>>(pnum, pM, ob, out);
}

// Round 18
// 128.617 us; speedup vs baseline: 1.2467x; 1.2467x over previous
//
#include <hip/hip_runtime.h>
#include <hip/hip_fp16.h>

// Problem constants (B,C,H,W = 2,3,96,96; D=32)
#define BB 2
#define CC 3
#define NN 9216   // 96*96
#define DD 32
#define NSPLIT 4                      // waves per block (key-quarters)
#define KSPLIT 2                      // blocks per 32-query group
#define KEYS_PER_WAVE (NN / (KSPLIT * NSPLIT))  // 1152
#define CHUNKS (KEYS_PER_WAVE / 64)   // 18
#define NGROUP (BB * NN / 32)         // 576 query groups
#define L2E 1.44269504f
#define PSTR 76                       // P row stride in halves: 38 words ≡ 6 mod 32
                                      // -> all 16 l16 lanes hit distinct banks,
                                      // cross-quad collisions <=2-way (free).
                                      // R16's 72 (36 ≡ 4 mod 32) was ~8-way:
                                      // 3.98M conflict-cycles ~= 15% of kernel.
#define SZH ((size_t)BB * NN * DD)    // halves per prep buffer (589,824)

typedef _Float16 half8 __attribute__((ext_vector_type(8)));
typedef _Float16 half4v __attribute__((ext_vector_type(4)));
typedef __fp16 fp16x2 __attribute__((ext_vector_type(2)));
typedef float float4v __attribute__((ext_vector_type(4)));

#define MFMA_K32(a, b, c) __builtin_amdgcn_mfma_f32_16x16x32_f16((a), (b), (c), 0, 0, 0)

// ---------------------------------------------------------------------------
// Fused prep. Blocks [0,288): K single-fp16 (fH) + Q hi/lo split (gH,gL),
// Q pre-scaled by log2(e) (R15: fL dropped, absmax margin verified 0.0156 <
// 0.02). Weights staged in LDS. Blocks [288,324): PROJECTED V — hP[c][n]
// plus a ONES row 3 (PV MFMA's row-3 accumulator computes the softmax
// denominator L for free).
// ---------------------------------------------------------------------------
__global__ __launch_bounds__(256) void prep_kernel(
    const float* __restrict__ img,
    const float* __restrict__ kw, const float* __restrict__ kb,
    const float* __restrict__ qw, const float* __restrict__ qb,
    const float* __restrict__ vw, const float* __restrict__ vb,
    const float* __restrict__ ow,
    _Float16* __restrict__ fH,
    _Float16* __restrict__ gH, _Float16* __restrict__ gL,
    _Float16* __restrict__ hP)
{
    __shared__ float wsm[256];   // kw[96] | qw[96] | kb[32] | qb[32]
    __shared__ float cwb[12];
    int bid = blockIdx.x;
    int t = threadIdx.x;
    if (bid < 288) {
        float v;
        if (t < 96)       v = kw[t];
        else if (t < 192) v = qw[t - 96];
        else if (t < 224) v = kb[t - 192];
        else              v = qb[t - 224];
        wsm[t] = v;
        __syncthreads();

        int id = bid * 256 + t;                    // [0, BB*NN*4)
        int part = id & 3;
        int n = (id >> 2) % NN;
        int b = (id >> 2) / NN;
        const float* xb = img + (size_t)b * CC * NN + n;
        float x0 = xb[0], x1 = xb[NN], x2 = xb[2 * NN];
        half8 fh, gh, gl;
#pragma unroll
        for (int j = 0; j < 8; j++) {
            int d = part * 8 + j;
            float fv = wsm[d * 3 + 0] * x0 + wsm[d * 3 + 1] * x1 +
                       wsm[d * 3 + 2] * x2 + wsm[192 + d];
            float gv = (wsm[96 + d * 3 + 0] * x0 + wsm[96 + d * 3 + 1] * x1 +
                        wsm[96 + d * 3 + 2] * x2 + wsm[224 + d]) * L2E;
            _Float16 ghi = (_Float16)gv;
            fh[j] = (_Float16)fv;
            gh[j] = ghi; gl[j] = (_Float16)(gv - (float)ghi);
        }
        size_t off = ((size_t)b * NN + n) * DD + part * 8;
        *(half8*)(fH + off) = fh;
        *(half8*)(gH + off) = gh;
        *(half8*)(gL + off) = gl;
    } else {
        if (t < 9) {
            int c = t / 3, k = t % 3;
            float s = 0.f;
#pragma unroll
            for (int d = 0; d < DD; d++) s += ow[c * DD + d] * vw[d * 3 + k];
            cwb[t] = s;
        } else if (t < 12) {
            int c = t - 9;
            float s = 0.f;
#pragma unroll
            for (int d = 0; d < DD; d++) s += ow[c * DD + d] * vb[d];
            cwb[9 + c] = s;
        }
        __syncthreads();
        const int N8 = NN / 8;
        int id = (bid - 288) * 256 + t;            // [0, BB*4*N8) = 9216
        int n8 = id % N8;
        int row = (id / N8) & 3;
        int b = id / (N8 * 4);
        half8 hv = {1, 1, 1, 1, 1, 1, 1, 1};       // row 3: ONES (L computation)
        if (row < 3) {
            const float* xb = img + (size_t)b * CC * NN + n8 * 8;
            float w0 = cwb[row * 3 + 0], w1 = cwb[row * 3 + 1],
                  w2 = cwb[row * 3 + 2], bv = cwb[9 + row];
#pragma unroll
            for (int j = 0; j < 8; j++)
                hv[j] = (_Float16)(w0 * xb[j] + w1 * xb[NN + j] + w2 * xb[2 * NN + j] + bv);
        }
        *(half8*)(hP + ((size_t)(b * 4 + row)) * NN + n8 * 8) = hv;
    }
}

// ---------------------------------------------------------------------------
// Per-tile softmax + P staging. Scores arrive RELATIVE (QK C-init = -mrun,
// R16); common path is P = exp2(s) with NO subtracts and a compare against
// THR=8. The trigger branch (rare) does the cross-lane max, rescales acc,
// subtracts delta in place, bumps mrun. mrun starts at 0: columns whose max
// stays < 8 never rescale — P <= 2^8, the defer-max fp16-safe invariant.
// ---------------------------------------------------------------------------
__device__ __forceinline__ void softmax_store(float4v (&s)[4], float& mrun,
                                              float4v& acc, _Float16* Pw,
                                              int l16, int quad)
{
    float a0 = fmaxf(fmaxf(s[0][0], s[0][1]), s[0][2]);
    float a1 = fmaxf(fmaxf(s[0][3], s[1][0]), s[1][1]);
    float a2 = fmaxf(fmaxf(s[1][2], s[1][3]), s[2][0]);
    float a3 = fmaxf(fmaxf(s[2][1], s[2][2]), s[2][3]);
    float a4 = fmaxf(fmaxf(s[3][0], s[3][1]), s[3][2]);
    float lmax = fmaxf(fmaxf(fmaxf(a0, a1), fmaxf(a2, a3)), fmaxf(a4, s[3][3]));
    if (__any(lmax > 8.f)) {
        float mx = fmaxf(lmax, __shfl_xor(lmax, 16, 64));
        mx = fmaxf(mx, __shfl_xor(mx, 32, 64));     // per-column max (quads)
        float d = fmaxf(mx, 0.f);                   // monotone running max
        float alpha = __builtin_amdgcn_exp2f(-d);
#pragma unroll
        for (int r = 0; r < 4; r++) acc[r] *= alpha;   // incl. L row
        mrun += d;
#pragma unroll
        for (int blk = 0; blk < 4; blk++)
#pragma unroll
            for (int j = 0; j < 4; j++) s[blk][j] -= d;   // trigger-only subs
    }
#pragma unroll
    for (int blk = 0; blk < 4; blk++) {
        float p0 = __builtin_amdgcn_exp2f(s[blk][0]);
        float p1 = __builtin_amdgcn_exp2f(s[blk][1]);
        float p2 = __builtin_amdgcn_exp2f(s[blk][2]);
        float p3 = __builtin_amdgcn_exp2f(s[blk][3]);
        union { fp16x2 h2[2]; half4v h4; } u;
        u.h2[0] = __builtin_amdgcn_cvt_pkrtz(p0, p1);
        u.h2[1] = __builtin_amdgcn_cvt_pkrtz(p2, p3);
        *(half4v*)(Pw + l16 * PSTR + blk * 16 + quad * 4) = u.h4;
    }
}

// ---------------------------------------------------------------------------
// Flash attention PARTIAL, cross-block split-K x2, 4 waves/block, 2 Q-tiles
// per wave — R16's proven structure (43.7 us, VGPR 40, no spill) with ONE
// delta: P row stride 72 -> 76 halves (PSTR), turning the ~8-way LDS bank
// conflicts (3.98M cycles/dispatch since R0) into <=2-way (free on wave64).
// R17's no-LDS variant removed the conflicts but +16 live regs -> 80 MB
// spill; this gets the conflict win at zero register cost.
// K single-fp16 (R15), C-init = -mrun fold (R16), single-K-buffer refill
// pipeline (R9), QK0->sm0->QK1->sm1->PV (R11), waves_per_eu(6,6).
// L is produced by the PV MFMA's ones-row (acc reg 3).
// ---------------------------------------------------------------------------
__global__ __launch_bounds__(256)
__attribute__((amdgpu_waves_per_eu(6, 6)))
void attn_partial_kernel(
    const _Float16* __restrict__ ws,
    float* __restrict__ pnum, float* __restrict__ pM)
{
    const _Float16* fH = ws;                 // K hi (single precision)
    const _Float16* gH = ws + SZH;           // Q hi (gL = +SZH)
    const _Float16* hP = ws + 3 * SZH;

    const int gb = blockIdx.x;             // 0 .. NGROUP*KSPLIT-1
    const int g  = gb / KSPLIT;            // query group
    const int ks = gb % KSPLIT;            // key-split id
    const int b = g / (NN / 32);
    const int m0 = (g % (NN / 32)) * 32;
    const int tid = threadIdx.x;
    const int w = tid >> 6;                // wave id 0..3 (key-quarter)
    const int lane = tid & 63;
    const int l16 = lane & 15;
    const int quad = lane >> 4;

    // Phase union: P staging (19456 B) / merge accumulators (rows c0..c2 + L)
    union SMem {
        _Float16 P[NSPLIT * 2 * 16 * PSTR];
        struct { float acc[NSPLIT][4][33]; float mbuf[NSPLIT][32]; } mg;
    };
    __shared__ __align__(16) SMem sm;

    // Q B-fragments for both tiles (hi + lo, log2e-scaled); gL = gH + SZH
    const _Float16* gHb = gH + ((size_t)b * NN + m0 + l16) * DD + quad * 8;
    half8 qh0 = *(const half8*)(gHb);
    half8 ql0 = *(const half8*)(gHb + SZH);
    half8 qh1 = *(const half8*)(gHb + (size_t)16 * DD);
    half8 ql1 = *(const half8*)(gHb + SZH + (size_t)16 * DD);

    float4v acc0 = {0,0,0,0};              // tile0: C[row][m=l16]; row3 = L
    float4v acc1 = {0,0,0,0};              // tile1
    float mrun0 = 0.f;                     // per-COLUMN running max, rel. 0
    float mrun1 = 0.f;

    const int nbase = ks * (NN / KSPLIT) + w * KEYS_PER_WAVE;
    // hP^T A-frag pointer: row = min(l16,3) (rows 3..15 read the ONES row)
    const int vrow = (l16 < 3) ? l16 : 3;
    const _Float16* vp = hP + ((size_t)(b * 4 + vrow)) * NN + nbase + quad * 8;
    const _Float16* kp = fH + ((size_t)b * NN + nbase + l16) * DD + quad * 8;
    _Float16* Pw0 = sm.P + (size_t)(w * 2 + 0) * 16 * PSTR;
    _Float16* Pw1 = sm.P + (size_t)(w * 2 + 1) * 16 * PSTR;

    // ---- prologue: chunk 0's K resident in the (single) K buffer
    half8 kC[4];
#pragma unroll
    for (int blk = 0; blk < 4; blk++)
        kC[blk] = *(const half8*)(kp + (size_t)(blk * 16) * DD);
    kp += (size_t)64 * DD;                 // -> chunk 1

    for (int c = 0; c < CHUNKS; ++c) {
        float4v s[4];
        // ---- QK tile 0: C-init = -mrun0 folds the softmax shift for free
        {
            float4v zm0 = {-mrun0, -mrun0, -mrun0, -mrun0};
#pragma unroll
            for (int blk = 0; blk < 4; blk++) {
                float4v t0 = MFMA_K32(kC[blk], ql0, zm0);
                s[blk] = MFMA_K32(kC[blk], qh0, t0);
            }
        }
        softmax_store(s, mrun0, acc0, Pw0, l16, quad);   // s dies here

        // ---- QK tile 1 (C-init = -mrun1); refill kC[blk] right after its
        //      last read (WAR), covered by sm1+PV (~300 cyc). Final iteration
        //      over-reads <=1 KB into the adjacent buffer (unused).
        {
            float4v zm1 = {-mrun1, -mrun1, -mrun1, -mrun1};
#pragma unroll
            for (int blk = 0; blk < 4; blk++) {
                float4v t1 = MFMA_K32(kC[blk], ql1, zm1);
                s[blk] = MFMA_K32(kC[blk], qh1, t1);
                kC[blk] = *(const half8*)(kp + (size_t)(blk * 16) * DD);
            }
        }
        kp += (size_t)64 * DD;

        // V frags for THIS chunk: issued here, used in PV (~400 cyc cover)
        half8 vA0 = *(const half8*)(vp);
        half8 vA1 = *(const half8*)(vp + 32);

        softmax_store(s, mrun1, acc1, Pw1, l16, quad);

        // ---- PV: A = hP^T (3 rows + ONES pad), B = P (LDS b128)
        //      => C[row=c, col=m=l16], row 3 accumulates L
        {
            half8 pf0 = *(const half8*)(Pw0 + l16 * PSTR + quad * 8);
            half8 pf1 = *(const half8*)(Pw0 + l16 * PSTR + 32 + quad * 8);
            acc0 = MFMA_K32(vA0, pf0, acc0);
            acc0 = MFMA_K32(vA1, pf1, acc0);
            half8 qf0 = *(const half8*)(Pw1 + l16 * PSTR + quad * 8);
            half8 qf1 = *(const half8*)(Pw1 + l16 * PSTR + 32 + quad * 8);
            acc1 = MFMA_K32(vA0, qf0, acc1);
            acc1 = MFMA_K32(vA1, qf1, acc1);
        }
        vp += 64;
    }

    __syncthreads();   // all waves done with sm.P — safe to reuse as sm.mg

    // ---- write per-wave partials (fp32) for the in-block merge
    if (quad == 0) {
#pragma unroll
        for (int r = 0; r < 4; r++) {      // rows c=0..2 and L (r=3)
            sm.mg.acc[w][r][l16]      = acc0[r];
            sm.mg.acc[w][r][l16 + 16] = acc1[r];
        }
        sm.mg.mbuf[w][l16]      = mrun0;
        sm.mg.mbuf[w][l16 + 16] = mrun1;
    }
    __syncthreads();

    // ---- merge NSPLIT waves -> un-normalized block partial -> global
    if (tid < 4 * 32) {
        int c = tid >> 5, m = tid & 31;    // c=3 row is L
        float M = sm.mg.mbuf[0][m];
#pragma unroll
        for (int s2 = 1; s2 < NSPLIT; s2++) M = fmaxf(M, sm.mg.mbuf[s2][m]);
        float v = 0.f;
#pragma unroll
        for (int s2 = 0; s2 < NSPLIT; s2++)
            v += sm.mg.acc[s2][c][m] * __builtin_amdgcn_exp2f(sm.mg.mbuf[s2][m] - M);
        pnum[(size_t)gb * 128 + tid] = v;
        if (c == 0) pM[gb * 32 + m] = M;
    }
}

// ---------------------------------------------------------------------------
// Final merge: KSPLIT-way log-sum-exp combine of the block partials, + ob,
// clamp. L lives in pnum row 3 (from the MFMA ones-row).
// ---------------------------------------------------------------------------
__global__ __launch_bounds__(128) void merge_kernel(
    const float* __restrict__ pnum, const float* __restrict__ pM,
    const float* __restrict__ ob, float* __restrict__ out)
{
    const int g = blockIdx.x;              // 0 .. NGROUP-1
    const int b = g / (NN / 32);
    const int m0 = (g % (NN / 32)) * 32;
    const int tid = threadIdx.x;

    if (tid < CC * 32) {
        int c = tid >> 5, m = tid & 31;
        int base = g * KSPLIT;
        float M = pM[base * 32 + m];
#pragma unroll
        for (int k = 1; k < KSPLIT; k++) M = fmaxf(M, pM[(base + k) * 32 + m]);
        float num = 0.f, L = 0.f;
#pragma unroll
        for (int k = 0; k < KSPLIT; k++) {
            float e = __builtin_amdgcn_exp2f(pM[(base + k) * 32 + m] - M);
            num += pnum[(size_t)(base + k) * 128 + c * 32 + m] * e;
            L   += pnum[(size_t)(base + k) * 128 + 96 + m] * e;
        }
        float o = num / L + ob[c];
        o = fminf(1.f, fmaxf(-1.f, o));
        out[((size_t)b * CC + c) * NN + m0 + m] = o;
    }
}

extern "C" void kernel_launch(void* const* d_in, const int* in_sizes, int n_in,
                              void* d_out, int out_size, void* d_ws, size_t ws_size,
                              hipStream_t stream) {
    const float* img = (const float*)d_in[0];
    const float* kw  = (const float*)d_in[1];
    const float* kb  = (const float*)d_in[2];
    const float* qw  = (const float*)d_in[3];
    const float* qb  = (const float*)d_in[4];
    const float* vw  = (const float*)d_in[5];
    const float* vb  = (const float*)d_in[6];
    const float* ow  = (const float*)d_in[7];
    const float* ob  = (const float*)d_in[8];
    float* out = (float*)d_out;

    // Workspace: fH,gH,gL fp16 (3.5 MB) + hP fp16 [B][4][N] (148 KB)
    // + pnum (590 KB) + pM (147 KB) ~= 4.4 MB
    _Float16* fH = (_Float16*)d_ws;
    _Float16* gH = fH + SZH;
    _Float16* gL = gH + SZH;
    _Float16* hP = gL + SZH;
    float* pnum = (float*)(hP + (size_t)BB * 4 * NN);
    float* pM   = pnum + (size_t)NGROUP * KSPLIT * 128;

    prep_kernel<<<324, 256, 0, stream>>>(img, kw, kb, qw, qb, vw, vb, ow,
                                         fH, gH, gL, hP);
    attn_partial_kernel<<<NGROUP * KSPLIT, 256, 0, stream>>>(
        (const _Float16*)d_ws, pnum, pM);
    merge_kernel<<<NGROUP, 128, 0, stream>>>(pnum, pM, ob, out);
}

// Round 19
// 108.740 us; speedup vs baseline: 1.4746x; 1.1828x over previous
//
#include <hip/hip_runtime.h>
#include <hip/hip_fp16.h>

// Problem constants (B,C,H,W = 2,3,96,96; D=32)
#define BB 2
#define CC 3
#define NN 9216   // 96*96
#define DD 32
#define NSPLIT 4                      // waves per block (key-quarters)
#define KSPLIT 2                      // blocks per 32-query group
#define KEYS_PER_WAVE (NN / (KSPLIT * NSPLIT))  // 1152
#define CHUNKS (KEYS_PER_WAVE / 64)   // 18
#define NGROUP (BB * NN / 32)         // 576 query groups
#define L2E 1.44269504f
#define SZH ((size_t)BB * NN * DD)    // halves per prep buffer (589,824)

typedef _Float16 half8 __attribute__((ext_vector_type(8)));
typedef _Float16 half4v __attribute__((ext_vector_type(4)));
typedef __fp16 fp16x2 __attribute__((ext_vector_type(2)));
typedef float float4v __attribute__((ext_vector_type(4)));

#define MFMA_K32(a, b, c) __builtin_amdgcn_mfma_f32_16x16x32_f16((a), (b), (c), 0, 0, 0)

// ---------------------------------------------------------------------------
// Fused prep. Blocks [0,288): K single-fp16 (fH) + Q hi/lo split (gH,gL),
// Q pre-scaled by log2(e). K is stored KEY-PERMUTED within each 32-key group
// (mem position b*16+q*4+j holds actual key q*8+b*4+j) so that QK's C-layout
// lands P directly in PV's B-fragment layout (R17, verified bit-identical).
// V (hP) stays LINEAR, defining the k-slot <-> actual-key identity.
// Blocks [288,324): PROJECTED V — hP[c][n] plus a ONES row 3 (PV MFMA's
// row-3 accumulator computes the softmax denominator L for free).
// ---------------------------------------------------------------------------
__global__ __launch_bounds__(256) void prep_kernel(
    const float* __restrict__ img,
    const float* __restrict__ kw, const float* __restrict__ kb,
    const float* __restrict__ qw, const float* __restrict__ qb,
    const float* __restrict__ vw, const float* __restrict__ vb,
    const float* __restrict__ ow,
    _Float16* __restrict__ fH,
    _Float16* __restrict__ gH, _Float16* __restrict__ gL,
    _Float16* __restrict__ hP)
{
    __shared__ float wsm[256];   // kw[96] | qw[96] | kb[32] | qb[32]
    __shared__ float cwb[12];
    int bid = blockIdx.x;
    int t = threadIdx.x;
    if (bid < 288) {
        float v;
        if (t < 96)       v = kw[t];
        else if (t < 192) v = qw[t - 96];
        else if (t < 224) v = kb[t - 192];
        else              v = qb[t - 224];
        wsm[t] = v;
        __syncthreads();

        int id = bid * 256 + t;                    // [0, BB*NN*4)
        int part = id & 3;
        int n = (id >> 2) % NN;
        int b = (id >> 2) / NN;
        const float* xb = img + (size_t)b * CC * NN + n;
        float x0 = xb[0], x1 = xb[NN], x2 = xb[2 * NN];
        half8 fh, gh, gl;
#pragma unroll
        for (int j = 0; j < 8; j++) {
            int d = part * 8 + j;
            float fv = wsm[d * 3 + 0] * x0 + wsm[d * 3 + 1] * x1 +
                       wsm[d * 3 + 2] * x2 + wsm[192 + d];
            float gv = (wsm[96 + d * 3 + 0] * x0 + wsm[96 + d * 3 + 1] * x1 +
                        wsm[96 + d * 3 + 2] * x2 + wsm[224 + d]) * L2E;
            _Float16 ghi = (_Float16)gv;
            fh[j] = (_Float16)fv;
            gh[j] = ghi; gl[j] = (_Float16)(gv - (float)ghi);
        }
        // K write: permuted position within the 32-key group (see header)
        int within = n & 31;
        int q  = within >> 3;      // 0..3
        int rm = within & 7;       // 0..7
        int bh = rm >> 2;          // 0..1
        int jj = rm & 3;           // 0..3
        int nperm = (n & ~31) | (bh << 4) | (q << 2) | jj;
        *(half8*)(fH + ((size_t)b * NN + nperm) * DD + part * 8) = fh;
        size_t off = ((size_t)b * NN + n) * DD + part * 8;
        *(half8*)(gH + off) = gh;
        *(half8*)(gL + off) = gl;
    } else {
        if (t < 9) {
            int c = t / 3, k = t % 3;
            float s = 0.f;
#pragma unroll
            for (int d = 0; d < DD; d++) s += ow[c * DD + d] * vw[d * 3 + k];
            cwb[t] = s;
        } else if (t < 12) {
            int c = t - 9;
            float s = 0.f;
#pragma unroll
            for (int d = 0; d < DD; d++) s += ow[c * DD + d] * vb[d];
            cwb[9 + c] = s;
        }
        __syncthreads();
        const int N8 = NN / 8;
        int id = (bid - 288) * 256 + t;            // [0, BB*4*N8) = 9216
        int n8 = id % N8;
        int row = (id / N8) & 3;
        int b = id / (N8 * 4);
        half8 hv = {1, 1, 1, 1, 1, 1, 1, 1};       // row 3: ONES (L computation)
        if (row < 3) {
            const float* xb = img + (size_t)b * CC * NN + n8 * 8;
            float w0 = cwb[row * 3 + 0], w1 = cwb[row * 3 + 1],
                  w2 = cwb[row * 3 + 2], bv = cwb[9 + row];
#pragma unroll
            for (int j = 0; j < 8; j++)
                hv[j] = (_Float16)(w0 * xb[j] + w1 * xb[NN + j] + w2 * xb[2 * NN + j] + bv);
        }
        *(half8*)(hP + ((size_t)(b * 4 + row)) * NN + n8 * 8) = hv;
    }
}

// ---------------------------------------------------------------------------
// Per-tile softmax + IN-REGISTER pack (no LDS — P goes straight into PV's
// B-fragment registers; the key permutation in prep makes layouts coincide).
// Scores arrive RELATIVE (QK C-init = -mrun, R16); common path is
// P = exp2(s), compare vs THR=8. Trigger branch (rare): cross-lane max,
// rescale acc, subtract delta, bump mrun. pa covers keys 0..31 (s[0],s[1]),
// pb keys 32..63 (s[2],s[3]).
// ---------------------------------------------------------------------------
__device__ __forceinline__ void softmax_pack(float4v (&s)[4], float& mrun,
                                             float4v& acc, half8& pa, half8& pb)
{
    float a0 = fmaxf(fmaxf(s[0][0], s[0][1]), s[0][2]);
    float a1 = fmaxf(fmaxf(s[0][3], s[1][0]), s[1][1]);
    float a2 = fmaxf(fmaxf(s[1][2], s[1][3]), s[2][0]);
    float a3 = fmaxf(fmaxf(s[2][1], s[2][2]), s[2][3]);
    float a4 = fmaxf(fmaxf(s[3][0], s[3][1]), s[3][2]);
    float lmax = fmaxf(fmaxf(fmaxf(a0, a1), fmaxf(a2, a3)), fmaxf(a4, s[3][3]));
    if (__any(lmax > 8.f)) {
        float mx = fmaxf(lmax, __shfl_xor(lmax, 16, 64));
        mx = fmaxf(mx, __shfl_xor(mx, 32, 64));     // per-column max (quads)
        float d = fmaxf(mx, 0.f);                   // monotone running max
        float alpha = __builtin_amdgcn_exp2f(-d);
#pragma unroll
        for (int r = 0; r < 4; r++) acc[r] *= alpha;   // incl. L row
        mrun += d;
#pragma unroll
        for (int blk = 0; blk < 4; blk++)
#pragma unroll
            for (int j = 0; j < 4; j++) s[blk][j] -= d;   // trigger-only subs
    }
    union { fp16x2 h2[4]; half8 h8; } ua, ub;
    ua.h2[0] = __builtin_amdgcn_cvt_pkrtz(__builtin_amdgcn_exp2f(s[0][0]),
                                          __builtin_amdgcn_exp2f(s[0][1]));
    ua.h2[1] = __builtin_amdgcn_cvt_pkrtz(__builtin_amdgcn_exp2f(s[0][2]),
                                          __builtin_amdgcn_exp2f(s[0][3]));
    ua.h2[2] = __builtin_amdgcn_cvt_pkrtz(__builtin_amdgcn_exp2f(s[1][0]),
                                          __builtin_amdgcn_exp2f(s[1][1]));
    ua.h2[3] = __builtin_amdgcn_cvt_pkrtz(__builtin_amdgcn_exp2f(s[1][2]),
                                          __builtin_amdgcn_exp2f(s[1][3]));
    ub.h2[0] = __builtin_amdgcn_cvt_pkrtz(__builtin_amdgcn_exp2f(s[2][0]),
                                          __builtin_amdgcn_exp2f(s[2][1]));
    ub.h2[1] = __builtin_amdgcn_cvt_pkrtz(__builtin_amdgcn_exp2f(s[2][2]),
                                          __builtin_amdgcn_exp2f(s[2][3]));
    ub.h2[2] = __builtin_amdgcn_cvt_pkrtz(__builtin_amdgcn_exp2f(s[3][0]),
                                          __builtin_amdgcn_exp2f(s[3][1]));
    ub.h2[3] = __builtin_amdgcn_cvt_pkrtz(__builtin_amdgcn_exp2f(s[3][2]),
                                          __builtin_amdgcn_exp2f(s[3][3]));
    pa = ua.h8; pb = ub.h8;
}

// ---------------------------------------------------------------------------
// Flash attention PARTIAL, cross-block split-K x2, 4 waves/block, 2 Q-tiles
// per wave. R19 = R17's no-LDS in-register P (bit-identical math, conflicts
// gone by construction) with the liveness fix R17 lacked: PV for tile 0 runs
// IMMEDIATELY after pack0 — pa0/pb0 die before QK1's s[4] goes live, so peak
// pressure returns to R16's proven envelope (R17 held them across QK1 and
// spilled 80 MB). R18's lesson folded in: the old P-LDS bank conflicts were
// never on the critical path, but the LDS round-trip's 12 ops + 2 lgkmcnt
// waits per chunk were — this deletes them. LDS = merge buffers only.
// K single-fp16 (R15), C-init = -mrun fold (R16), single-K-buffer refill
// pipeline (R9), waves_per_eu(6,6).
// L is produced by the PV MFMA's ones-row (acc reg 3).
// ---------------------------------------------------------------------------
__global__ __launch_bounds__(256)
__attribute__((amdgpu_waves_per_eu(6, 6)))
void attn_partial_kernel(
    const _Float16* __restrict__ ws,
    float* __restrict__ pnum, float* __restrict__ pM)
{
    const _Float16* fH = ws;                 // K hi (key-permuted)
    const _Float16* gH = ws + SZH;           // Q hi (gL = +SZH)
    const _Float16* hP = ws + 3 * SZH;       // projected V (linear)

    const int gb = blockIdx.x;             // 0 .. NGROUP*KSPLIT-1
    const int g  = gb / KSPLIT;            // query group
    const int ks = gb % KSPLIT;            // key-split id
    const int b = g / (NN / 32);
    const int m0 = (g % (NN / 32)) * 32;
    const int tid = threadIdx.x;
    const int w = tid >> 6;                // wave id 0..3 (key-quarter)
    const int lane = tid & 63;
    const int l16 = lane & 15;
    const int quad = lane >> 4;

    // Merge buffers only (~4.7 KB — P staging is gone)
    __shared__ __align__(16) struct {
        float acc[NSPLIT][4][33];
        float mbuf[NSPLIT][32];
    } sm;

    // Q B-fragments for both tiles (hi + lo, log2e-scaled); gL = gH + SZH
    const _Float16* gHb = gH + ((size_t)b * NN + m0 + l16) * DD + quad * 8;
    half8 qh0 = *(const half8*)(gHb);
    half8 ql0 = *(const half8*)(gHb + SZH);
    half8 qh1 = *(const half8*)(gHb + (size_t)16 * DD);
    half8 ql1 = *(const half8*)(gHb + SZH + (size_t)16 * DD);

    float4v acc0 = {0,0,0,0};              // tile0: C[row][m=l16]; row3 = L
    float4v acc1 = {0,0,0,0};              // tile1
    float mrun0 = 0.f;                     // per-COLUMN running max, rel. 0
    float mrun1 = 0.f;

    const int nbase = ks * (NN / KSPLIT) + w * KEYS_PER_WAVE;
    // hP^T A-frag pointer: row = min(l16,3) (rows 3..15 read the ONES row)
    const int vrow = (l16 < 3) ? l16 : 3;
    const _Float16* vp = hP + ((size_t)(b * 4 + vrow)) * NN + nbase + quad * 8;
    const _Float16* kp = fH + ((size_t)b * NN + nbase + l16) * DD + quad * 8;

    // ---- prologue: chunk 0's K resident in the (single) K buffer
    half8 kC[4];
#pragma unroll
    for (int blk = 0; blk < 4; blk++)
        kC[blk] = *(const half8*)(kp + (size_t)(blk * 16) * DD);
    kp += (size_t)64 * DD;                 // -> chunk 1

    for (int c = 0; c < CHUNKS; ++c) {
        // V frags for THIS chunk: issued first, used in PV0/PV1
        half8 vA0 = *(const half8*)(vp);
        half8 vA1 = *(const half8*)(vp + 32);

        float4v s[4];
        // ---- QK tile 0: C-init = -mrun0 folds the softmax shift for free
        {
            float4v zm0 = {-mrun0, -mrun0, -mrun0, -mrun0};
#pragma unroll
            for (int blk = 0; blk < 4; blk++) {
                float4v t0 = MFMA_K32(kC[blk], ql0, zm0);
                s[blk] = MFMA_K32(kC[blk], qh0, t0);
            }
        }
        // ---- pack0 -> PV0 immediately (pa0/pb0 die before QK1: the R17
        //      spill was holding them across QK1's s[4] liveness peak)
        {
            half8 pa0, pb0;
            softmax_pack(s, mrun0, acc0, pa0, pb0);
            acc0 = MFMA_K32(vA0, pa0, acc0);
            acc0 = MFMA_K32(vA1, pb0, acc0);
        }

        // ---- QK tile 1 (C-init = -mrun1); refill kC[blk] right after its
        //      last read (WAR), covered by pack1+PV1 (~250 cyc). Final
        //      iteration over-reads <=1 KB into the adjacent buffer (unused).
        {
            float4v zm1 = {-mrun1, -mrun1, -mrun1, -mrun1};
#pragma unroll
            for (int blk = 0; blk < 4; blk++) {
                float4v t1 = MFMA_K32(kC[blk], ql1, zm1);
                s[blk] = MFMA_K32(kC[blk], qh1, t1);
                kC[blk] = *(const half8*)(kp + (size_t)(blk * 16) * DD);
            }
        }
        kp += (size_t)64 * DD;

        {
            half8 pa1, pb1;
            softmax_pack(s, mrun1, acc1, pa1, pb1);
            acc1 = MFMA_K32(vA0, pa1, acc1);
            acc1 = MFMA_K32(vA1, pb1, acc1);
        }
        vp += 64;
    }

    // ---- write per-wave partials (fp32) for the in-block merge
    if (quad == 0) {
#pragma unroll
        for (int r = 0; r < 4; r++) {      // rows c=0..2 and L (r=3)
            sm.acc[w][r][l16]      = acc0[r];
            sm.acc[w][r][l16 + 16] = acc1[r];
        }
        sm.mbuf[w][l16]      = mrun0;
        sm.mbuf[w][l16 + 16] = mrun1;
    }
    __syncthreads();

    // ---- merge NSPLIT waves -> un-normalized block partial -> global
    if (tid < 4 * 32) {
        int c = tid >> 5, m = tid & 31;    // c=3 row is L
        float M = sm.mbuf[0][m];
#pragma unroll
        for (int s2 = 1; s2 < NSPLIT; s2++) M = fmaxf(M, sm.mbuf[s2][m]);
        float v = 0.f;
#pragma unroll
        for (int s2 = 0; s2 < NSPLIT; s2++)
            v += sm.acc[s2][c][m] * __builtin_amdgcn_exp2f(sm.mbuf[s2][m] - M);
        pnum[(size_t)gb * 128 + tid] = v;
        if (c == 0) pM[gb * 32 + m] = M;
    }
}

// ---------------------------------------------------------------------------
// Final merge: KSPLIT-way log-sum-exp combine of the block partials, + ob,
// clamp. L lives in pnum row 3 (from the MFMA ones-row).
// ---------------------------------------------------------------------------
__global__ __launch_bounds__(128) void merge_kernel(
    const float* __restrict__ pnum, const float* __restrict__ pM,
    const float* __restrict__ ob, float* __restrict__ out)
{
    const int g = blockIdx.x;              // 0 .. NGROUP-1
    const int b = g / (NN / 32);
    const int m0 = (g % (NN / 32)) * 32;
    const int tid = threadIdx.x;

    if (tid < CC * 32) {
        int c = tid >> 5, m = tid & 31;
        int base = g * KSPLIT;
        float M = pM[base * 32 + m];
#pragma unroll
        for (int k = 1; k < KSPLIT; k++) M = fmaxf(M, pM[(base + k) * 32 + m]);
        float num = 0.f, L = 0.f;
#pragma unroll
        for (int k = 0; k < KSPLIT; k++) {
            float e = __builtin_amdgcn_exp2f(pM[(base + k) * 32 + m] - M);
            num += pnum[(size_t)(base + k) * 128 + c * 32 + m] * e;
            L   += pnum[(size_t)(base + k) * 128 + 96 + m] * e;
        }
        float o = num / L + ob[c];
        o = fminf(1.f, fmaxf(-1.f, o));
        out[((size_t)b * CC + c) * NN + m0 + m] = o;
    }
}

extern "C" void kernel_launch(void* const* d_in, const int* in_sizes, int n_in,
                              void* d_out, int out_size, void* d_ws, size_t ws_size,
                              hipStream_t stream) {
    const float* img = (const float*)d_in[0];
    const float* kw  = (const float*)d_in[1];
    const float* kb  = (const float*)d_in[2];
    const float* qw  = (const float*)d_in[3];
    const float* qb  = (const float*)d_in[4];
    const float* vw  = (const float*)d_in[5];
    const float* vb  = (const float*)d_in[6];
    const float* ow  = (const float*)d_in[7];
    const float* ob  = (const float*)d_in[8];
    float* out = (float*)d_out;

    // Workspace: fH,gH,gL fp16 (3.5 MB) + hP fp16 [B][4][N] (148 KB)
    // + pnum (590 KB) + pM (147 KB) ~= 4.4 MB
    _Float16* fH = (_Float16*)d_ws;
    _Float16* gH = fH + SZH;
    _Float16* gL = gH + SZH;
    _Float16* hP = gL + SZH;
    float* pnum = (float*)(hP + (size_t)BB * 4 * NN);
    float* pM   = pnum + (size_t)NGROUP * KSPLIT * 128;

    prep_kernel<<<324, 256, 0, stream>>>(img, kw, kb, qw, qb, vw, vb, ow,
                                         fH, gH, gL, hP);
    attn_partial_kernel<<<NGROUP * KSPLIT, 256, 0, stream>>>(
        (const _Float16*)d_ws, pnum, pM);
    merge_kernel<<<NGROUP, 128, 0, stream>>>(pnum, pM, ob, out);
}